// Round 1
// baseline (78.616 us; speedup 1.0000x reference)
//
#include <hip/hip_runtime.h>
#include <math.h>

// AUC surrogate loss = (1/(P*N)) * sum_{i:pos,j:neg} sigmoid(p_j - p_i)
//
// R11 = R6 histogram cross-correlation, restructured 3 kernels -> 2:
//   - hist_k (HB=4 blocks): private LDS hists, linear-interp deposit, plain-store
//     copies to ws; also zero-inits the acc/ticket words (kernel-boundary release
//     makes them visible to conv — still zero memsets, zero wbl2).
//   - conv_k (257 blocks): merges the 4 copies on load (HB 16->4 cuts the per-block
//     prologue from 128 to 32 loads/thread — per-block time IS kernel time at
//     <=257 co-resident blocks), then folds the old reduce_k into the last conv
//     block via a fence-free atomic ticket: atomicAdd partial -> waitcnt (forced
//     by consuming the returned value) -> atomicAdd ticket; last arriver reads
//     the final sum with atomicAdd(acc,0) and writes out. Device-scope atomics
//     are cross-XCD coherent; no release/acquire, no wbl2 (R7's 57us lesson).
// Exact bilinear interp of sigmoid on a 2049-node grid over [-12,12];
// err ~1e-5 << 9.9e-3 threshold. Session floor remains the harness's 268MB
// ws re-poison (~39.4us @ 85% HBM) + reset dispatches, outside kernel control.

#define NODES 2049                 // grid nodes (2048 intervals)
#define NPAD  2052                 // padded hist stride
#define SLEN  4097                 // S[m+2048], m = k-l in [-2048,2048]
#define KC    8                    // k's per conv block
#define HB    4                    // histogram blocks (was 16; conv merges HB copies)

static constexpr float LO    = -12.0f;
static constexpr float DELTA = 24.0f / 2048.0f;
static constexpr float INVD  = 2048.0f / 24.0f;
static constexpr float LOG2E = 1.4426950408889634f;

// ---- histogram: HB blocks, private LDS hists, plain-store copies -----------

__global__ __launch_bounds__(1024)
void hist_k(const float* __restrict__ pred, const int* __restrict__ yt, int B,
            float* __restrict__ g_h /* HB x 2 x NPAD */,
            int* __restrict__ g_Pc /* HB */,
            float* __restrict__ g_acc, int* __restrict__ g_tk) {
    __shared__ float h[2 * NPAD];
    const int t = threadIdx.x;
    const int b = blockIdx.x;

    if (b == 0 && t == 0) { g_acc[0] = 0.f; g_tk[0] = 0; }  // visible to conv via dispatch boundary

    for (int i = t; i < 2 * NPAD; i += 1024) h[i] = 0.f;
    __syncthreads();

    int cp = 0;
    for (int e = b * 1024 + t; e < B; e += HB * 1024) {     // 4 coalesced rounds
        float p = pred[e];
        int   c = yt[e];
        float x = (p - LO) * INVD;
        x = fminf(fmaxf(x, 0.f), 2047.999f);   // 8-sigma grid; clamp no-op in practice
        int   k = (int)x;
        float f = x - (float)k;
        int base = (c == 1) ? 0 : NPAD;
        cp += (c == 1);
        atomicAdd(&h[base + k],     1.f - f);
        atomicAdd(&h[base + k + 1], f);
    }
    __syncthreads();

    float* dst = g_h + (size_t)b * 2 * NPAD;
    for (int i = t; i < NODES; i += 1024) {
        dst[i]        = h[i];
        dst[NPAD + i] = h[NPAD + i];
    }

    #pragma unroll
    for (int off = 32; off; off >>= 1) cp += __shfl_down(cp, off, 64);
    __shared__ int wc[16];
    if ((t & 63) == 0) wc[t >> 6] = cp;
    __syncthreads();
    if (t == 0) {
        int s = 0;
        #pragma unroll
        for (int k = 0; k < 16; ++k) s += wc[k];
        g_Pc[b] = s;
    }
}

// ---- correlation + fused finalize: 257 blocks x 256 thr --------------------

__global__ __launch_bounds__(256)
void conv_k(const float* __restrict__ g_h, const int* __restrict__ g_Pc,
            float* __restrict__ g_acc, int* __restrict__ g_tk,
            int B, int nBlk, float* __restrict__ out) {
    __shared__ float sS[SLEN];
    __shared__ float sN[NODES];
    const int t = threadIdx.x;
    const int bk = blockIdx.x;

    // early P-count gather (hides latency under the prologue); lane 0 of wave 0
    // ends up holding P = sum(g_Pc[0..HB-1])
    int pv = (t < HB) ? g_Pc[t] : 0;
    pv += __shfl_down(pv, 2, 64);
    pv += __shfl_down(pv, 1, 64);

    for (int i = t; i < NODES; i += 256) {        // merge HB hN copies (L2/L3-hot)
        float s = 0.f;
        #pragma unroll
        for (int b = 0; b < HB; ++b) s += g_h[(size_t)b * 2 * NPAD + NPAD + i];
        sN[i] = s;
    }
    for (int i = t; i < SLEN; i += 256) {
        // S[i] = sigmoid(-(i-2048)*DELTA) = 1/(1+e^{(i-2048)*DELTA})
        float d = (float)(i - 2048) * DELTA;
        float e = __builtin_amdgcn_exp2f(d * LOG2E);
        sS[i] = __builtin_amdgcn_rcpf(1.f + e);
    }
    __syncthreads();

    float acc = 0.f;
    #pragma unroll
    for (int kk = 0; kk < KC; ++kk) {
        int k = bk * KC + kk;
        if (k < NODES) {
            float hPk = 0.f;                      // merge HB hP[k] scalars (broadcast loads)
            #pragma unroll
            for (int b = 0; b < HB; ++b) hPk += g_h[(size_t)b * 2 * NPAD + k];
            if (hPk != 0.f) {
                const float* Sk = &sS[k + 2048];
                for (int l = t; l < NODES; l += 256)
                    acc += hPk * (sN[l] * Sk[-l]);   // stride-1 LDS, conflict-free
            }
        }
    }

    #pragma unroll
    for (int off = 32; off; off >>= 1) acc += __shfl_down(acc, off, 64);
    __shared__ float wa[4];
    if ((t & 63) == 0) wa[t >> 6] = acc;
    __syncthreads();
    if (t == 0) {
        float p = (wa[0] + wa[1]) + (wa[2] + wa[3]);
        // fence-free atomic ticket: acc-add must COMPLETE before ticket-add issues.
        float old = atomicAdd(g_acc, p);
        asm volatile("" :: "v"(old));   // consume returned value -> s_waitcnt vmcnt(0)
        int tk = atomicAdd(g_tk, 1);
        if (tk == nBlk - 1) {
            // last arriver: every other block's acc-add completed before its
            // ticket-add, so the coherent-point value is final.
            float S = atomicAdd(g_acc, 0.f);
            double P = (double)pv;
            double N = (double)B - P;
            out[0] = (float)((double)S / (P * N));
        }
    }
}

extern "C" void kernel_launch(void* const* d_in, const int* in_sizes, int n_in,
                              void* d_out, int out_size, void* d_ws, size_t ws_size,
                              hipStream_t stream) {
    const float* pred = (const float*)d_in[0];
    const int*   yt   = (const int*)d_in[1];
    const int B = in_sizes[0];
    float* out = (float*)d_out;

    float* g_h   = (float*)d_ws;                      // HB*2*NPAD floats
    int*   g_Pc  = (int*)(g_h + (size_t)HB * 2 * NPAD);
    float* g_acc = (float*)(g_Pc + 16);
    int*   g_tk  = (int*)(g_acc + 1);

    const int nBlk = (NODES + KC - 1) / KC;           // 257

    hist_k<<<HB, 1024, 0, stream>>>(pred, yt, B, g_h, g_Pc, g_acc, g_tk);
    conv_k<<<nBlk, 256, 0, stream>>>(g_h, g_Pc, g_acc, g_tk, B, nBlk, out);
}

// Round 2
// 70.985 us; speedup vs baseline: 1.1075x; 1.1075x over previous
//
#include <hip/hip_runtime.h>
#include <math.h>

// AUC surrogate loss = (1/(P*N)) * sum_{i:pos,j:neg} sigmoid(p_j - p_i)
//
// R12 = R10 (best measured: 71.35us) with two conservative changes:
//   - HB 16->8: hist keeps 8-way CU parallelism (R11's HB=4 regressed), conv's
//     per-block merge traffic halves (33.7MB -> 16.9MB of L3 reads).
//   - float4 merge + copy-out: conv prologue goes from 128 scalar L3 loads per
//     thread to 16 dwordx4 loads (same coalescing, 8x fewer issue slots).
// R11's atomic-ticket finalize is reverted: 257 serialized same-address far
// atomics + vmcnt(0) drains on conv's tail cost more than reduce_k's dispatch.
//
// Histogram cross-correlation: deposit preds on a 2049-node grid over [-12,12]
// with linear-interp weights;
//   sum = SUM_k SUM_l hP[k] * hN[l] * sigmoid((l-k)*delta)
// (exact bilinear interp of sigmoid; err ~3e-6 << 9.9e-3 threshold).
// 8 blocks build private LDS hists and plain-store copies to ws; conv merges
// the 8 copies on load (L2/L3-hot). Zero global atomics, zero memsets, zero
// release/acquire (no wbl2 — R7's 57us lesson). Session floor is the harness's
// 268MB ws re-poison (~39.4us @ 85% HBM) + reset dispatches, outside kernel
// control.

#define NODES 2049                 // grid nodes (2048 intervals)
#define NPAD  2052                 // padded hist stride (x4B = 16B-aligned)
#define SLEN  4097                 // S[m+2048], m = k-l in [-2048,2048]
#define KC    8                    // k's per conv block
#define HB    8                    // histogram blocks (conv merges HB copies)

static constexpr float LO    = -12.0f;
static constexpr float DELTA = 24.0f / 2048.0f;
static constexpr float INVD  = 2048.0f / 24.0f;
static constexpr float LOG2E = 1.4426950408889634f;

// ---- histogram: HB blocks, private LDS hists, plain-store copies -----------

__global__ __launch_bounds__(1024)
void hist_k(const float* __restrict__ pred, const int* __restrict__ yt, int B,
            float* __restrict__ g_h /* HB x 2 x NPAD */,
            int* __restrict__ g_Pc /* HB */) {
    __shared__ __align__(16) float h[2 * NPAD];
    const int t = threadIdx.x;
    const int b = blockIdx.x;

    for (int i = t; i < 2 * NPAD; i += 1024) h[i] = 0.f;
    __syncthreads();

    int cp = 0;
    for (int e = b * 1024 + t; e < B; e += HB * 1024) {     // 2 coalesced rounds
        float p = pred[e];
        int   c = yt[e];
        float x = (p - LO) * INVD;
        x = fminf(fmaxf(x, 0.f), 2047.999f);   // 8-sigma grid; clamp no-op in practice
        int   k = (int)x;
        float f = x - (float)k;
        int base = (c == 1) ? 0 : NPAD;
        cp += (c == 1);
        atomicAdd(&h[base + k],     1.f - f);
        atomicAdd(&h[base + k + 1], f);
    }
    __syncthreads();

    // vectorized copy-out: 2048 floats per array via float4, + tail node 2048
    float* dst = g_h + (size_t)b * 2 * NPAD;
    if (t < 512) {
        ((float4*)dst)[t]          = ((const float4*)h)[t];
        ((float4*)(dst + NPAD))[t] = ((const float4*)(h + NPAD))[t];
    }
    if (t == 0) {
        dst[2048]        = h[2048];
        dst[NPAD + 2048] = h[NPAD + 2048];
    }

    #pragma unroll
    for (int off = 32; off; off >>= 1) cp += __shfl_down(cp, off, 64);
    __shared__ int wc[16];
    if ((t & 63) == 0) wc[t >> 6] = cp;
    __syncthreads();
    if (t == 0) {
        int s = 0;
        #pragma unroll
        for (int k = 0; k < 16; ++k) s += wc[k];
        g_Pc[b] = s;
    }
}

// ---- correlation: 257 blocks x 256 thr over 2049 x 2049 node pairs ---------

__global__ __launch_bounds__(256)
void conv_k(const float* __restrict__ g_h, float* __restrict__ partial) {
    __shared__ __align__(16) float sS[SLEN];
    __shared__ __align__(16) float sN[NODES];
    const int t = threadIdx.x;
    const int bk = blockIdx.x;

    // merge HB hN copies (L2/L3-hot), float4: 2 iters x HB dwordx4 loads/thread
    for (int i = t; i < 512; i += 256) {
        float4 s = make_float4(0.f, 0.f, 0.f, 0.f);
        #pragma unroll
        for (int b = 0; b < HB; ++b) {
            float4 v = ((const float4*)(g_h + (size_t)b * 2 * NPAD + NPAD))[i];
            s.x += v.x; s.y += v.y; s.z += v.z; s.w += v.w;
        }
        ((float4*)sN)[i] = s;
    }
    if (t == 0) {
        float s = 0.f;
        #pragma unroll
        for (int b = 0; b < HB; ++b) s += g_h[(size_t)b * 2 * NPAD + NPAD + 2048];
        sN[2048] = s;
    }
    for (int i = t; i < SLEN; i += 256) {
        // S[i] = sigmoid(-(i-2048)*DELTA) = 1/(1+e^{(i-2048)*DELTA})
        float d = (float)(i - 2048) * DELTA;
        float e = __builtin_amdgcn_exp2f(d * LOG2E);
        sS[i] = __builtin_amdgcn_rcpf(1.f + e);
    }
    __syncthreads();

    float acc = 0.f;
    #pragma unroll
    for (int kk = 0; kk < KC; ++kk) {
        int k = bk * KC + kk;
        if (k < NODES) {
            float hPk = 0.f;                      // merge HB hP[k] scalars (broadcast)
            #pragma unroll
            for (int b = 0; b < HB; ++b) hPk += g_h[(size_t)b * 2 * NPAD + k];
            if (hPk != 0.f) {
                const float* Sk = &sS[k + 2048];
                for (int l = t; l < NODES; l += 256)
                    acc += hPk * (sN[l] * Sk[-l]);   // stride-1 LDS, conflict-free
            }
        }
    }

    #pragma unroll
    for (int off = 32; off; off >>= 1) acc += __shfl_down(acc, off, 64);
    __shared__ float wa[4];
    if ((t & 63) == 0) wa[t >> 6] = acc;
    __syncthreads();
    if (t == 0) partial[bk] = (wa[0] + wa[1]) + (wa[2] + wa[3]);
}

// ---- finalize ---------------------------------------------------------------

__global__ __launch_bounds__(256)
void reduce_k(const float* __restrict__ partial, int nPart,
              const int* __restrict__ g_Pc, int B, float* __restrict__ out) {
    const int t = threadIdx.x;
    double s = 0.0;
    for (int i = t; i < nPart; i += 256) s += (double)partial[i];
    int cp = 0;
    if (t < HB) cp = g_Pc[t];
    #pragma unroll
    for (int off = 32; off; off >>= 1) {
        s  += __shfl_down(s, off, 64);
        cp += __shfl_down(cp, off, 64);
    }
    __shared__ double wa[4];
    __shared__ int    wp[4];
    if ((t & 63) == 0) { wa[t >> 6] = s; wp[t >> 6] = cp; }
    __syncthreads();
    if (t == 0) {
        double S = (wa[0] + wa[1]) + (wa[2] + wa[3]);
        double P = (double)(wp[0] + wp[1] + wp[2] + wp[3]);
        double N = (double)B - P;
        out[0] = (float)(S / (P * N));
    }
}

extern "C" void kernel_launch(void* const* d_in, const int* in_sizes, int n_in,
                              void* d_out, int out_size, void* d_ws, size_t ws_size,
                              hipStream_t stream) {
    const float* pred = (const float*)d_in[0];
    const int*   yt   = (const int*)d_in[1];
    const int B = in_sizes[0];
    float* out = (float*)d_out;

    float* g_h  = (float*)d_ws;                       // HB*2*NPAD floats
    int*   g_Pc = (int*)(g_h + (size_t)HB * 2 * NPAD);
    float* part = (float*)(g_Pc + 64);                // 257 floats

    const int nBlk = (NODES + KC - 1) / KC;           // 257

    hist_k<<<HB, 1024, 0, stream>>>(pred, yt, B, g_h, g_Pc);
    conv_k<<<nBlk, 256, 0, stream>>>(g_h, part);
    reduce_k<<<1, 256, 0, stream>>>(part, nBlk, g_Pc, B, out);
}

// Round 3
// 68.149 us; speedup vs baseline: 1.1536x; 1.0416x over previous
//
#include <hip/hip_runtime.h>
#include <math.h>

// AUC surrogate loss = (1/(P*N)) * sum_{i:pos,j:neg} sigmoid(p_j - p_i)
//
// R13 = R12 (best measured: 70.99us) with conv-only changes:
//   - per-block sigmoid table shrunk 4097 -> KC+2048=2056 entries (a block only
//     touches S[k+2048-l] for its KC k's): transcendental prologue 16 -> 9
//     iters/thread, LDS 24.6KB -> 16.4KB.
//   - inner loop restructured as sum_l sN[l] * dot(hPk[0..7], S[...]): hPk
//     hoisted to thread-uniform registers (scalarized loads), sN read once per
//     8 FMAs -> 81 LDS reads/thread vs 144, 9 loop iters vs 64.
//   - bk tail guarded: k >= NODES forces hPk=0 (pad region would be garbage).
// hist_k / reduce_k verbatim from R12 (HB=8, float4 copies).
//
// Histogram cross-correlation: deposit preds on a 2049-node grid over [-12,12]
// with linear-interp weights;
//   sum = SUM_k SUM_l hP[k] * hN[l] * sigmoid((l-k)*delta)
// (exact bilinear interp of sigmoid; err ~3e-6 << 9.9e-3 threshold).
// Zero global atomics, zero memsets, zero release/acquire. Session floor is the
// harness's 268MB ws re-poison (~39.3us @ 85% HBM) + resets, outside kernel
// control.

#define NODES 2049                 // grid nodes (2048 intervals)
#define NPAD  2052                 // padded hist stride (x4B = 16B-aligned)
#define TLEN  (2048 + 8)           // per-block sigmoid table span (KC=8)
#define KC    8                    // k's per conv block
#define HB    8                    // histogram blocks (conv merges HB copies)

static constexpr float LO    = -12.0f;
static constexpr float DELTA = 24.0f / 2048.0f;
static constexpr float INVD  = 2048.0f / 24.0f;
static constexpr float LOG2E = 1.4426950408889634f;

// ---- histogram: HB blocks, private LDS hists, plain-store copies -----------

__global__ __launch_bounds__(1024)
void hist_k(const float* __restrict__ pred, const int* __restrict__ yt, int B,
            float* __restrict__ g_h /* HB x 2 x NPAD */,
            int* __restrict__ g_Pc /* HB */) {
    __shared__ __align__(16) float h[2 * NPAD];
    const int t = threadIdx.x;
    const int b = blockIdx.x;

    for (int i = t; i < 2 * NPAD; i += 1024) h[i] = 0.f;
    __syncthreads();

    int cp = 0;
    for (int e = b * 1024 + t; e < B; e += HB * 1024) {     // 2 coalesced rounds
        float p = pred[e];
        int   c = yt[e];
        float x = (p - LO) * INVD;
        x = fminf(fmaxf(x, 0.f), 2047.999f);   // 8-sigma grid; clamp no-op in practice
        int   k = (int)x;
        float f = x - (float)k;
        int base = (c == 1) ? 0 : NPAD;
        cp += (c == 1);
        atomicAdd(&h[base + k],     1.f - f);
        atomicAdd(&h[base + k + 1], f);
    }
    __syncthreads();

    // vectorized copy-out: 2048 floats per array via float4, + tail node 2048
    float* dst = g_h + (size_t)b * 2 * NPAD;
    if (t < 512) {
        ((float4*)dst)[t]          = ((const float4*)h)[t];
        ((float4*)(dst + NPAD))[t] = ((const float4*)(h + NPAD))[t];
    }
    if (t == 0) {
        dst[2048]        = h[2048];
        dst[NPAD + 2048] = h[NPAD + 2048];
    }

    #pragma unroll
    for (int off = 32; off; off >>= 1) cp += __shfl_down(cp, off, 64);
    __shared__ int wc[16];
    if ((t & 63) == 0) wc[t >> 6] = cp;
    __syncthreads();
    if (t == 0) {
        int s = 0;
        #pragma unroll
        for (int k = 0; k < 16; ++k) s += wc[k];
        g_Pc[b] = s;
    }
}

// ---- correlation: 257 blocks x 256 thr over 2049 x 2049 node pairs ---------

__global__ __launch_bounds__(256)
void conv_k(const float* __restrict__ g_h, float* __restrict__ partial) {
    __shared__ __align__(16) float sT[TLEN];   // S[bk*KC + j], j in [0, TLEN)
    __shared__ __align__(16) float sN[NODES];
    const int t = threadIdx.x;
    const int bk = blockIdx.x;

    // merge HB hN copies (L2/L3-hot), float4: 2 iters x HB dwordx4 loads/thread
    for (int i = t; i < 512; i += 256) {
        float4 s = make_float4(0.f, 0.f, 0.f, 0.f);
        #pragma unroll
        for (int b = 0; b < HB; ++b) {
            float4 v = ((const float4*)(g_h + (size_t)b * 2 * NPAD + NPAD))[i];
            s.x += v.x; s.y += v.y; s.z += v.z; s.w += v.w;
        }
        ((float4*)sN)[i] = s;
    }
    if (t == 0) {
        float s = 0.f;
        #pragma unroll
        for (int b = 0; b < HB; ++b) s += g_h[(size_t)b * 2 * NPAD + NPAD + 2048];
        sN[2048] = s;
    }
    // shifted sigmoid table: sT[j] = sigmoid(-(bk*KC + j - 2048)*DELTA)
    //   -> sT[kk + 2048 - l] = sigmoid((l-k)*DELTA), k = bk*KC+kk.
    // Tail (bk=256, j past node range): exp2->inf, rcp->0; finite, and the
    // matching hPk is forced to 0 below.
    for (int j = t; j < TLEN; j += 256) {
        float d = (float)(bk * KC + j - 2048) * DELTA;
        float e = __builtin_amdgcn_exp2f(d * LOG2E);
        sT[j] = __builtin_amdgcn_rcpf(1.f + e);
    }

    // hPk[0..KC): thread-uniform -> scalarized broadcast loads, overlap latency
    // with the LDS fill above.
    float hv[KC];
    bool anynz = false;
    #pragma unroll
    for (int kk = 0; kk < KC; ++kk) {
        int k = bk * KC + kk;
        float s = 0.f;
        if (k < NODES) {
            #pragma unroll
            for (int b = 0; b < HB; ++b) s += g_h[(size_t)b * 2 * NPAD + k];
        }
        hv[kk] = s;
        anynz = anynz || (s != 0.f);
    }
    __syncthreads();

    float acc = 0.f;
    if (anynz) {
        for (int l = t; l < NODES; l += 256) {
            float nv = sN[l];
            const float* sp = &sT[2048 - l];      // sp[kk] ascending, stride-1 LDS
            #pragma unroll
            for (int kk = 0; kk < KC; ++kk)
                acc += hv[kk] * (nv * sp[kk]);
        }
    }

    #pragma unroll
    for (int off = 32; off; off >>= 1) acc += __shfl_down(acc, off, 64);
    __shared__ float wa[4];
    if ((t & 63) == 0) wa[t >> 6] = acc;
    __syncthreads();
    if (t == 0) partial[bk] = (wa[0] + wa[1]) + (wa[2] + wa[3]);
}

// ---- finalize ---------------------------------------------------------------

__global__ __launch_bounds__(256)
void reduce_k(const float* __restrict__ partial, int nPart,
              const int* __restrict__ g_Pc, int B, float* __restrict__ out) {
    const int t = threadIdx.x;
    double s = 0.0;
    for (int i = t; i < nPart; i += 256) s += (double)partial[i];
    int cp = 0;
    if (t < HB) cp = g_Pc[t];
    #pragma unroll
    for (int off = 32; off; off >>= 1) {
        s  += __shfl_down(s, off, 64);
        cp += __shfl_down(cp, off, 64);
    }
    __shared__ double wa[4];
    __shared__ int    wp[4];
    if ((t & 63) == 0) { wa[t >> 6] = s; wp[t >> 6] = cp; }
    __syncthreads();
    if (t == 0) {
        double S = (wa[0] + wa[1]) + (wa[2] + wa[3]);
        double P = (double)(wp[0] + wp[1] + wp[2] + wp[3]);
        double N = (double)B - P;
        out[0] = (float)(S / (P * N));
    }
}

extern "C" void kernel_launch(void* const* d_in, const int* in_sizes, int n_in,
                              void* d_out, int out_size, void* d_ws, size_t ws_size,
                              hipStream_t stream) {
    const float* pred = (const float*)d_in[0];
    const int*   yt   = (const int*)d_in[1];
    const int B = in_sizes[0];
    float* out = (float*)d_out;

    float* g_h  = (float*)d_ws;                       // HB*2*NPAD floats
    int*   g_Pc = (int*)(g_h + (size_t)HB * 2 * NPAD);
    float* part = (float*)(g_Pc + 64);                // 257 floats

    const int nBlk = (NODES + KC - 1) / KC;           // 257

    hist_k<<<HB, 1024, 0, stream>>>(pred, yt, B, g_h, g_Pc);
    conv_k<<<nBlk, 256, 0, stream>>>(g_h, part);
    reduce_k<<<1, 256, 0, stream>>>(part, nBlk, g_Pc, B, out);
}